// Round 14
// baseline (190.792 us; speedup 1.0000x reference)
//
#include <hip/hip_runtime.h>
#include <stdint.h>

// QuantizedLinear: out = x @ dequant(q,s)^T + bias
// Pure-i8 path (R11 numerics). R14: same 128x256/BK=128 block + R11 sync
// skeleton, but 4 waves x (64x128 wave tile) instead of 8 x (64x64):
// A-row panels shared by 2 waves instead of 4 -> per-step LDS reads drop
// 128KB -> 96KB (the measured binding resource), MFMA/wave/step doubles.
#define M_DIM 2048
#define K_DIM 4096
#define N_DIM 11008
#define KB2   (K_DIM / 2)
#define NGRP  32

#define TBM 128
#define TBN 256
#define TBK 128
#define NT  (K_DIM / TBK)     // 32 K-steps
#define BUF_B 49152           // bytes per LDS buffer: A 128x128 (16KB) + B 256x128 (32KB)

#define XRANGE 5.0f
#define XSCALE (127.0f / XRANGE)
#define XINV   (XRANGE / 127.0f)

// fallback tile (bf16 fused path, no workspace)
#define BM 128
#define BN 128
#define BK 64

typedef __attribute__((ext_vector_type(4))) int   i32x4;
typedef __attribute__((ext_vector_type(4))) float f32x4;
typedef __attribute__((ext_vector_type(8))) short bf16x8;

__device__ __forceinline__ unsigned short f2bf(float f) {
  union { float f; unsigned u; } v; v.f = f;
  return (unsigned short)((v.u + 0x7FFFu + ((v.u >> 16) & 1u)) >> 16);
}

__device__ __forceinline__ void gload_lds16(const void* g, void* l) {
  __builtin_amdgcn_global_load_lds(
      (__attribute__((address_space(1))) void*)(g),
      (__attribute__((address_space(3))) void*)(l), 16, 0, 0);
}

__device__ __forceinline__ int q127(float v) {
  float qf = fminf(127.0f, fmaxf(-127.0f, rintf(v * XSCALE)));
  return (int)qf;
}

// ---------------- prepass: x f32 -> i8 (fixed scale) ----------------
__global__ void quant_x_kernel(const float* __restrict__ x,
                               signed char* __restrict__ xq) {
  const size_t total = (size_t)M_DIM * K_DIM / 16;
  for (size_t u = (size_t)blockIdx.x * blockDim.x + threadIdx.x; u < total;
       u += (size_t)gridDim.x * blockDim.x) {
    const float4* src = (const float4*)(x + u * 16);
    int4 o;
    int* op = (int*)&o;
#pragma unroll
    for (int i = 0; i < 4; ++i) {
      float4 f = src[i];
      int q0 = q127(f.x), q1 = q127(f.y), q2 = q127(f.z), q3 = q127(f.w);
      op[i] = (q0 & 255) | ((q1 & 255) << 8) | ((q2 & 255) << 16) | ((q3 & 255) << 24);
    }
    *(int4*)(xq + u * 16) = o;
  }
}

// ---------------- prepass: per-row scale prep ----------------
__global__ void rowscale_kernel(const float* __restrict__ s,
                                float* __restrict__ d_inv,
                                float* __restrict__ rowScale) {
  int o = blockIdx.x * blockDim.x + threadIdx.x;
  if (o >= N_DIM) return;
  const float4* sp = (const float4*)(s + o * NGRP);
  float m = 0.0f;
#pragma unroll
  for (int i = 0; i < 8; ++i) {
    float4 v = sp[i];
    m = fmaxf(m, fmaxf(fmaxf(v.x, v.y), fmaxf(v.z, v.w)));
  }
  float d = 8.0f * m / 127.0f;
  d_inv[o] = 1.0f / d;
  rowScale[o] = d * XINV;
}

// ---------------- prepass: packed int4 -> requantized i8 W [N, K] ----------------
__global__ void unpack_w_kernel(const int* __restrict__ q,
                                const float* __restrict__ s,
                                const float* __restrict__ d_inv,
                                signed char* __restrict__ W) {
  const size_t total = (size_t)N_DIM * KB2 / 8;
  for (size_t u = (size_t)blockIdx.x * blockDim.x + threadIdx.x; u < total;
       u += (size_t)gridDim.x * blockDim.x) {
    size_t qi = u * 8;
    unsigned o = (unsigned)(qi >> 11);
    unsigned c = (unsigned)(qi & 2047);
    float sc = s[o * NGRP + (c >> 6)] * d_inv[o];
    int4 v0 = *(const int4*)(q + qi);
    int4 v1 = *(const int4*)(q + qi + 4);
    int4 out;
    int* op = (int*)&out;
#pragma unroll
    for (int i = 0; i < 2; ++i) {
      const int* vv = i ? (const int*)&v1 : (const int*)&v0;
#pragma unroll
      for (int p = 0; p < 2; ++p) {
        int a = vv[p * 2], b = vv[p * 2 + 1];
        int q0 = (int)rintf((float)((a & 15) - 8) * sc);
        int q1 = (int)rintf((float)(((a >> 4) & 15) - 8) * sc);
        int q2 = (int)rintf((float)((b & 15) - 8) * sc);
        int q3 = (int)rintf((float)(((b >> 4) & 15) - 8) * sc);
        op[i * 2 + p] = (q0 & 255) | ((q1 & 255) << 8) | ((q2 & 255) << 16) | ((q3 & 255) << 24);
      }
    }
    *(int4*)(W + qi * 2) = out;
  }
}

// ---------------- main GEMM: C = Xq * Wq^T (i8), epilogue row scale + bias ----------------
// 128x256 tile, BK=128, 4 waves (2M x 2N), wave 64x128: iacc[4][8] i32.
// Per step per wave: 24 ds_read_b128 + 64 MFMA (compiler-interleaved);
// 3-buffer LDS rotation, distance-2 prefetch, counted vmcnt(12) at step end
// (12 staging loads/tile with 256 threads).
// Swizzle for 128B rows (8 x 16B slots), both-sides: slot ^= row&7.
__global__ __launch_bounds__(256, 1) void gemm_i8_kernel(
    const signed char* __restrict__ A, const signed char* __restrict__ B,
    const float* __restrict__ rowScale, const float* __restrict__ bias,
    float* __restrict__ C) {
  __shared__ signed char lds[3 * BUF_B];  // 144 KB

  const int tid = threadIdx.x;
  const int w = tid >> 6, lane = tid & 63;

  // T1: XCD-chunked bijective swizzle (688 = 8 * 86), m-fast within XCD.
  const int hw = blockIdx.x;
  const int wg = (hw & 7) * 86 + (hw >> 3);
  const int m0 = (wg % 16) * TBM;
  const int n0 = (wg / 16) * TBN;

  // staging: 12 issues/tile (A:4, B:8), each issue = 256 thr x 16B = 4KB = 32 rows.
  // thread row-within-issue = tid>>3, 16B slot = tid&7.
  // Inverse swizzle on global k: slot s of row r holds k-chunk s ^ (r&7).
  const int srow = tid >> 3;
  const int kx = (((tid & 7) ^ ((tid >> 3) & 7)) << 4);  // bytes
  const signed char* Ag = A + (size_t)(m0 + srow) * K_DIM + kx;
  const signed char* Bg = B + (size_t)(n0 + srow) * K_DIM + kx;
  const int wBase = w * 1024;  // wave-uniform LDS staging base (bytes)

#define STAGE(bufo, t2) {                                                      \
    const signed char* a_ = Ag + (size_t)(t2) * TBK;                           \
    const signed char* b_ = Bg + (size_t)(t2) * TBK;                           \
    _Pragma("unroll")                                                          \
    for (int ii = 0; ii < 4; ++ii)                                             \
      gload_lds16(a_ + (size_t)(ii * 32) * K_DIM,                              \
                  lds + (bufo) + ii * 4096 + wBase);                           \
    _Pragma("unroll")                                                          \
    for (int ii = 0; ii < 8; ++ii)                                             \
      gload_lds16(b_ + (size_t)(ii * 32) * K_DIM,                              \
                  lds + (bufo) + 16384 + ii * 4096 + wBase);                   \
  }

  // ds_read addressing (swizzled): byte = row*128 + ((kk*4+lq) ^ (row&7))*16
  const int lane16 = lane & 15, lq = lane >> 4;
  const int wm = (w >> 1) * 64, wn = (w & 1) * 128;
  int aOff[4][2], bOff[8][2];
#pragma unroll
  for (int i = 0; i < 4; ++i)
#pragma unroll
    for (int kk = 0; kk < 2; ++kk)
      aOff[i][kk] = (wm + i * 16 + lane16) * 128 + (((kk * 4 + lq) ^ (lane16 & 7)) << 4);
#pragma unroll
  for (int j = 0; j < 8; ++j)
#pragma unroll
    for (int kk = 0; kk < 2; ++kk)
      bOff[j][kk] = 16384 + (wn + j * 16 + lane16) * 128 + (((kk * 4 + lq) ^ (lane16 & 7)) << 4);

  i32x4 iacc[4][8];
#pragma unroll
  for (int i = 0; i < 4; ++i)
#pragma unroll
    for (int j = 0; j < 8; ++j) iacc[i][j] = (i32x4){0, 0, 0, 0};

  // prologue: tiles 0,1 (24 loads); wait until only tile1's 12 remain
  STAGE(0, 0);
  STAGE(BUF_B, 1);
  asm volatile("s_waitcnt vmcnt(12)" ::: "memory");
  __builtin_amdgcn_s_barrier();

  int cur = 0, stg = 2 * BUF_B;
  for (int t = 0; t < NT; ++t) {
    if (t + 2 < NT) STAGE(stg, t + 2);

    const signed char* Lb = lds + cur;
    i32x4 av[4][2], bv[8][2];
#pragma unroll
    for (int i = 0; i < 4; ++i)
#pragma unroll
      for (int kk = 0; kk < 2; ++kk)
        av[i][kk] = *(const i32x4*)(Lb + aOff[i][kk]);
#pragma unroll
    for (int j = 0; j < 8; ++j)
#pragma unroll
      for (int kk = 0; kk < 2; ++kk)
        bv[j][kk] = *(const i32x4*)(Lb + bOff[j][kk]);

    __builtin_amdgcn_s_setprio(1);
#pragma unroll
    for (int u = 0; u < 32; ++u) {
      const int pi = u & 3, pj = u >> 2;
      i32x4 tmp_ = __builtin_amdgcn_mfma_i32_16x16x64_i8(av[pi][0], bv[pj][0],
                                                         iacc[pi][pj], 0, 0, 0);
      iacc[pi][pj] = __builtin_amdgcn_mfma_i32_16x16x64_i8(av[pi][1], bv[pj][1],
                                                           tmp_, 0, 0, 0);
    }
    __builtin_amdgcn_s_setprio(0);

    if (t == NT - 1) break;
    if (t == NT - 2) {
      asm volatile("s_waitcnt vmcnt(0)" ::: "memory");  // final tile must land
    } else {
      asm volatile("s_waitcnt vmcnt(12)" ::: "memory");  // keep tile t+2 in flight
    }
    __builtin_amdgcn_s_barrier();
    cur = (cur == 2 * BUF_B) ? 0 : cur + BUF_B;
    stg = (stg == 2 * BUF_B) ? 0 : stg + BUF_B;
  }
#undef STAGE

  // epilogue: D mapping col=lane&15, row=(lane>>4)*4+r
  const int row0 = m0 + wm + (lane >> 4) * 4;
  const int col0 = n0 + wn + lane16;
#pragma unroll
  for (int j = 0; j < 8; ++j) {
    const int col = col0 + j * 16;
    float rs = rowScale[col];
    float bvs = bias[col];
#pragma unroll
    for (int i = 0; i < 4; ++i) {
#pragma unroll
      for (int r = 0; r < 4; ++r) {
        C[(size_t)(row0 + i * 16 + r) * N_DIM + col] =
            (float)iacc[i][j][r] * rs + bvs;
      }
    }
  }
}

// ---------------- fallback: fused bf16 dequant GEMM (no workspace needed) ----------------
__global__ __launch_bounds__(256, 2) void gemm_fused_kernel(
    const float* __restrict__ x, const int* __restrict__ q,
    const float* __restrict__ s, const float* __restrict__ bias,
    float* __restrict__ C) {
  __shared__ unsigned short As[BM * BK];
  __shared__ unsigned short Bs[BN * BK];

  const int tid = threadIdx.x;
  const int wave = tid >> 6, lane = tid & 63;
  const int m0 = blockIdx.y * BM, n0 = blockIdx.x * BN;
  const int wm = (wave >> 1) * 64, wn = (wave & 1) * 64;

  f32x4 acc[4][4] = {};

  const int r2 = tid >> 1;
  const int kh = (tid & 1) * 32;
  const float* xg = x + (size_t)(m0 + r2) * K_DIM + kh;
  const int* qg = q + (size_t)(n0 + r2) * KB2 + (tid & 1) * 16;
  const float* sg = s + (size_t)(n0 + r2) * NGRP;
  unsigned short* Asp = &As[r2 * BK + kh];
  unsigned short* Bsp = &Bs[r2 * BK + kh];

  const int lane16 = lane & 15;
  const int kq = (lane >> 4) * 8;

  for (int t = 0; t < K_DIM / BK; ++t) {
    union { unsigned short h[8]; bf16x8 v; } oA[4], oB[4];
#pragma unroll
    for (int j = 0; j < 4; ++j) {
      float4 f0 = *(const float4*)(xg + t * BK + j * 8);
      float4 f1 = *(const float4*)(xg + t * BK + j * 8 + 4);
      oA[j].h[0] = f2bf(f0.x); oA[j].h[1] = f2bf(f0.y); oA[j].h[2] = f2bf(f0.z); oA[j].h[3] = f2bf(f0.w);
      oA[j].h[4] = f2bf(f1.x); oA[j].h[5] = f2bf(f1.y); oA[j].h[6] = f2bf(f1.z); oA[j].h[7] = f2bf(f1.w);
    }
    float sc = sg[t >> 1];
#pragma unroll
    for (int j = 0; j < 4; ++j) {
      int4 qv = *(const int4*)(qg + t * 32 + j * 4);
      int b;
      b = qv.x; oB[j].h[0] = f2bf((float)((b & 15) - 8) * sc); oB[j].h[1] = f2bf((float)(((b >> 4) & 15) - 8) * sc);
      b = qv.y; oB[j].h[2] = f2bf((float)((b & 15) - 8) * sc); oB[j].h[3] = f2bf((float)(((b >> 4) & 15) - 8) * sc);
      b = qv.z; oB[j].h[4] = f2bf((float)((b & 15) - 8) * sc); oB[j].h[5] = f2bf((float)(((b >> 4) & 15) - 8) * sc);
      b = qv.w; oB[j].h[6] = f2bf((float)((b & 15) - 8) * sc); oB[j].h[7] = f2bf((float)(((b >> 4) & 15) - 8) * sc);
    }
    __syncthreads();
#pragma unroll
    for (int j = 0; j < 4; ++j) {
      *(bf16x8*)(Asp + j * 8) = oA[j].v;
      *(bf16x8*)(Bsp + j * 8) = oB[j].v;
    }
    __syncthreads();
#pragma unroll
    for (int kk = 0; kk < 2; ++kk) {
      const int ko = kk * 32 + kq;
      bf16x8 av[4], bv[4];
#pragma unroll
      for (int i = 0; i < 4; ++i)
        av[i] = *(const bf16x8*)&As[(wm + i * 16 + lane16) * BK + ko];
#pragma unroll
      for (int i = 0; i < 4; ++i)
        bv[i] = *(const bf16x8*)&Bs[(wn + i * 16 + lane16) * BK + ko];
#pragma unroll
      for (int i = 0; i < 4; ++i)
#pragma unroll
        for (int j = 0; j < 4; ++j)
          acc[i][j] = __builtin_amdgcn_mfma_f32_16x16x32_bf16(av[i], bv[j], acc[i][j], 0, 0, 0);
    }
  }

  const int col0 = n0 + wn + lane16;
  const int row0 = m0 + wm + (lane >> 4) * 4;
#pragma unroll
  for (int j = 0; j < 4; ++j) {
    float bvs = bias[col0 + j * 16];
#pragma unroll
    for (int i = 0; i < 4; ++i) {
#pragma unroll
      for (int r = 0; r < 4; ++r) {
        C[(size_t)(row0 + i * 16 + r) * N_DIM + (col0 + j * 16)] = acc[i][j][r] + bvs;
      }
    }
  }
}

extern "C" void kernel_launch(void* const* d_in, const int* in_sizes, int n_in,
                              void* d_out, int out_size, void* d_ws, size_t ws_size,
                              hipStream_t stream) {
  const float* x = (const float*)d_in[0];
  const int* q = (const int*)d_in[1];
  const float* s = (const float*)d_in[2];
  const float* b = (const float*)d_in[3];
  float* out = (float*)d_out;

  const size_t w_bytes = (size_t)N_DIM * K_DIM;          // 45,088,768 (i8 W)
  const size_t x_bytes = (size_t)M_DIM * K_DIM;          // 8,388,608  (i8 x)
  const size_t r_bytes = (size_t)N_DIM * 4;              // 44,032 each
  const size_t need = w_bytes + x_bytes + 2 * r_bytes;   // ~54 MB

  if (ws_size >= need) {
    signed char* Wq = (signed char*)d_ws;
    signed char* Xq = Wq + w_bytes;
    float* d_inv = (float*)(Wq + w_bytes + x_bytes);
    float* rowScale = d_inv + N_DIM;
    quant_x_kernel<<<dim3(2048), dim3(256), 0, stream>>>(x, Xq);
    rowscale_kernel<<<dim3((N_DIM + 255) / 256), dim3(256), 0, stream>>>(s, d_inv, rowScale);
    unpack_w_kernel<<<dim3(2048), dim3(256), 0, stream>>>(q, s, d_inv, Wq);
    gemm_i8_kernel<<<dim3((N_DIM / TBN) * (M_DIM / TBM)), dim3(256), 0, stream>>>(Xq, Wq, rowScale, b, out);
  } else {
    gemm_fused_kernel<<<dim3(N_DIM / BN, M_DIM / BM), dim3(256), 0, stream>>>(x, q, s, b, out);
  }
}

// Round 15
// 160.375 us; speedup vs baseline: 1.1897x; 1.1897x over previous
//
#include <hip/hip_runtime.h>
#include <stdint.h>

// QuantizedLinear: out = x @ dequant(q,s)^T + bias
// Pure-i8 path. R15 = R11 skeleton verbatim (proven best: 128x256, BK=128,
// 8 waves x 64x64, 3-buffer distance-2, counted vmcnt(6), both-sides swizzle)
// with the MFMA swapped 16x16x64 -> 32x32x32 (µbench 4404 vs 3944 TOPS, and
// half the MFMA instruction count per step). Wave tile = 2x2 frags of 32x32.
// ds_read pattern unchanged in count/width (16 x b128 per wave-step).
#define M_DIM 2048
#define K_DIM 4096
#define N_DIM 11008
#define KB2   (K_DIM / 2)
#define NGRP  32

#define TBM 128
#define TBN 256
#define TBK 128
#define NT  (K_DIM / TBK)     // 32 K-steps
#define BUF_B 49152           // bytes per LDS buffer: A 128x128 (16KB) + B 256x128 (32KB)

#define XRANGE 5.0f
#define XSCALE (127.0f / XRANGE)
#define XINV   (XRANGE / 127.0f)

// fallback tile (bf16 fused path, no workspace)
#define BM 128
#define BN 128
#define BK 64

typedef __attribute__((ext_vector_type(4)))  int   i32x4;
typedef __attribute__((ext_vector_type(16))) int   i32x16;
typedef __attribute__((ext_vector_type(4)))  float f32x4;
typedef __attribute__((ext_vector_type(8)))  short bf16x8;

__device__ __forceinline__ unsigned short f2bf(float f) {
  union { float f; unsigned u; } v; v.f = f;
  return (unsigned short)((v.u + 0x7FFFu + ((v.u >> 16) & 1u)) >> 16);
}

__device__ __forceinline__ void gload_lds16(const void* g, void* l) {
  __builtin_amdgcn_global_load_lds(
      (__attribute__((address_space(1))) void*)(g),
      (__attribute__((address_space(3))) void*)(l), 16, 0, 0);
}

__device__ __forceinline__ int q127(float v) {
  float qf = fminf(127.0f, fmaxf(-127.0f, rintf(v * XSCALE)));
  return (int)qf;
}

// ---------------- prepass: x f32 -> i8 (fixed scale) ----------------
__global__ void quant_x_kernel(const float* __restrict__ x,
                               signed char* __restrict__ xq) {
  const size_t total = (size_t)M_DIM * K_DIM / 16;
  for (size_t u = (size_t)blockIdx.x * blockDim.x + threadIdx.x; u < total;
       u += (size_t)gridDim.x * blockDim.x) {
    const float4* src = (const float4*)(x + u * 16);
    int4 o;
    int* op = (int*)&o;
#pragma unroll
    for (int i = 0; i < 4; ++i) {
      float4 f = src[i];
      int q0 = q127(f.x), q1 = q127(f.y), q2 = q127(f.z), q3 = q127(f.w);
      op[i] = (q0 & 255) | ((q1 & 255) << 8) | ((q2 & 255) << 16) | ((q3 & 255) << 24);
    }
    *(int4*)(xq + u * 16) = o;
  }
}

// ---------------- prepass: per-row scale prep ----------------
__global__ void rowscale_kernel(const float* __restrict__ s,
                                float* __restrict__ d_inv,
                                float* __restrict__ rowScale) {
  int o = blockIdx.x * blockDim.x + threadIdx.x;
  if (o >= N_DIM) return;
  const float4* sp = (const float4*)(s + o * NGRP);
  float m = 0.0f;
#pragma unroll
  for (int i = 0; i < 8; ++i) {
    float4 v = sp[i];
    m = fmaxf(m, fmaxf(fmaxf(v.x, v.y), fmaxf(v.z, v.w)));
  }
  float d = 8.0f * m / 127.0f;
  d_inv[o] = 1.0f / d;
  rowScale[o] = d * XINV;
}

// ---------------- prepass: packed int4 -> requantized i8 W [N, K] ----------------
__global__ void unpack_w_kernel(const int* __restrict__ q,
                                const float* __restrict__ s,
                                const float* __restrict__ d_inv,
                                signed char* __restrict__ W) {
  const size_t total = (size_t)N_DIM * KB2 / 8;
  for (size_t u = (size_t)blockIdx.x * blockDim.x + threadIdx.x; u < total;
       u += (size_t)gridDim.x * blockDim.x) {
    size_t qi = u * 8;
    unsigned o = (unsigned)(qi >> 11);
    unsigned c = (unsigned)(qi & 2047);
    float sc = s[o * NGRP + (c >> 6)] * d_inv[o];
    int4 v0 = *(const int4*)(q + qi);
    int4 v1 = *(const int4*)(q + qi + 4);
    int4 out;
    int* op = (int*)&out;
#pragma unroll
    for (int i = 0; i < 2; ++i) {
      const int* vv = i ? (const int*)&v1 : (const int*)&v0;
#pragma unroll
      for (int p = 0; p < 2; ++p) {
        int a = vv[p * 2], b = vv[p * 2 + 1];
        int q0 = (int)rintf((float)((a & 15) - 8) * sc);
        int q1 = (int)rintf((float)(((a >> 4) & 15) - 8) * sc);
        int q2 = (int)rintf((float)((b & 15) - 8) * sc);
        int q3 = (int)rintf((float)(((b >> 4) & 15) - 8) * sc);
        op[i * 2 + p] = (q0 & 255) | ((q1 & 255) << 8) | ((q2 & 255) << 16) | ((q3 & 255) << 24);
      }
    }
    *(int4*)(W + qi * 2) = out;
  }
}

// ---------------- main GEMM: C = Xq * Wq^T (i8), epilogue row scale + bias ----------------
// 128x256 tile, BK=128, 8 waves (2M x 4N), wave 64x64 = 2x2 frags of 32x32.
// mfma_i32_32x32x32_i8: A/B frag = 16 consecutive i8 at row=lane&31,
// k = (lane>>5)*16; per step 16 ds_read_b128 + 16 MFMA.
// 3-buffer LDS rotation, distance-2 prefetch, counted vmcnt(6) at step end.
// Swizzle for 128B rows (8 x 16B slots), both-sides: slot ^= row&7.
__global__ __launch_bounds__(512, 2) void gemm_i8_kernel(
    const signed char* __restrict__ A, const signed char* __restrict__ B,
    const float* __restrict__ rowScale, const float* __restrict__ bias,
    float* __restrict__ C) {
  __shared__ signed char lds[3 * BUF_B];  // 144 KB

  const int tid = threadIdx.x;
  const int w = tid >> 6, lane = tid & 63;

  // T1: XCD-chunked bijective swizzle (688 = 8 * 86), m-fast within XCD.
  const int hw = blockIdx.x;
  const int wg = (hw & 7) * 86 + (hw >> 3);
  const int m0 = (wg % 16) * TBM;
  const int n0 = (wg / 16) * TBN;

  // staging (R11 verbatim): 6 issues/tile (A:2, B:4), 512 thr x 16B = 64 rows.
  // Inverse swizzle on global k: slot s of row r holds k-chunk s ^ (r&7).
  const int srow = tid >> 3;
  const int kx = (((tid & 7) ^ ((tid >> 3) & 7)) << 4);  // bytes
  const signed char* Ag = A + (size_t)(m0 + srow) * K_DIM + kx;
  const signed char* Bg = B + (size_t)(n0 + srow) * K_DIM + kx;
  const int wBase = w * 1024;  // wave-uniform LDS staging base (bytes)

#define STAGE(bufo, t2) {                                                      \
    const signed char* a_ = Ag + (size_t)(t2) * TBK;                           \
    const signed char* b_ = Bg + (size_t)(t2) * TBK;                           \
    gload_lds16(a_,                       lds + (bufo) + wBase);               \
    gload_lds16(a_ + (size_t)64 * K_DIM,  lds + (bufo) + 8192 + wBase);        \
    gload_lds16(b_,                       lds + (bufo) + 16384 + wBase);       \
    gload_lds16(b_ + (size_t)64 * K_DIM,  lds + (bufo) + 24576 + wBase);       \
    gload_lds16(b_ + (size_t)128 * K_DIM, lds + (bufo) + 32768 + wBase);       \
    gload_lds16(b_ + (size_t)192 * K_DIM, lds + (bufo) + 40960 + wBase);       \
  }

  // ds_read addressing (swizzled): 32x32 frag f, k-slice ks (32 k wide):
  // row = base + f*32 + (lane&31); slot = ks*2 + (lane>>5); byte =
  // row*128 + (slot ^ (row&7))*16. row&7 == lane&7.
  const int lane31 = lane & 31, lhi = lane >> 5, l7 = lane & 7;
  const int wm = (w >> 2) * 64, wn = (w & 3) * 64;
  int aOff[2][4], bOff[2][4];
#pragma unroll
  for (int f = 0; f < 2; ++f)
#pragma unroll
    for (int ks = 0; ks < 4; ++ks) {
      const int sl = (((ks << 1) | lhi) ^ l7) << 4;
      aOff[f][ks] = (wm + f * 32 + lane31) * 128 + sl;
      bOff[f][ks] = 16384 + (wn + f * 32 + lane31) * 128 + sl;
    }

  i32x16 iacc[2][2];
#pragma unroll
  for (int i = 0; i < 2; ++i)
#pragma unroll
    for (int j = 0; j < 2; ++j)
#pragma unroll
      for (int r = 0; r < 16; ++r) iacc[i][j][r] = 0;

  // prologue: tiles 0,1 (12 loads); wait until only tile1's 6 remain
  STAGE(0, 0);
  STAGE(BUF_B, 1);
  asm volatile("s_waitcnt vmcnt(6)" ::: "memory");
  __builtin_amdgcn_s_barrier();

  int cur = 0, stg = 2 * BUF_B;
  for (int t = 0; t < NT; ++t) {
    if (t + 2 < NT) STAGE(stg, t + 2);

    const signed char* Lb = lds + cur;
    i32x4 av[2][4], bv[2][4];
#pragma unroll
    for (int f = 0; f < 2; ++f)
#pragma unroll
      for (int ks = 0; ks < 4; ++ks) {
        av[f][ks] = *(const i32x4*)(Lb + aOff[f][ks]);
        bv[f][ks] = *(const i32x4*)(Lb + bOff[f][ks]);
      }

    __builtin_amdgcn_s_setprio(1);
#pragma unroll
    for (int ks = 0; ks < 4; ++ks)
#pragma unroll
      for (int fi = 0; fi < 2; ++fi)
#pragma unroll
        for (int fj = 0; fj < 2; ++fj)
          iacc[fi][fj] = __builtin_amdgcn_mfma_i32_32x32x32_i8(
              av[fi][ks], bv[fj][ks], iacc[fi][fj], 0, 0, 0);
    __builtin_amdgcn_s_setprio(0);

    if (t == NT - 1) break;
    if (t == NT - 2) {
      asm volatile("s_waitcnt vmcnt(0)" ::: "memory");  // final tile must land
    } else {
      asm volatile("s_waitcnt vmcnt(6)" ::: "memory");  // keep tile t+2 in flight
    }
    __builtin_amdgcn_s_barrier();
    cur = (cur == 2 * BUF_B) ? 0 : cur + BUF_B;
    stg = (stg == 2 * BUF_B) ? 0 : stg + BUF_B;
  }
#undef STAGE

  // epilogue: 32x32 D mapping (m74/m101-verified): col = lane&31,
  // row = (reg&3) + 8*(reg>>2) + 4*(lane>>5), reg in [0,16).
  const int rowb = m0 + wm + 4 * lhi;
  const int col0 = n0 + wn + lane31;
#pragma unroll
  for (int fj = 0; fj < 2; ++fj) {
    const int col = col0 + fj * 32;
    float rs = rowScale[col];
    float bvs = bias[col];
#pragma unroll
    for (int fi = 0; fi < 2; ++fi) {
#pragma unroll
      for (int r = 0; r < 16; ++r) {
        const int row = rowb + fi * 32 + (r & 3) + 8 * (r >> 2);
        C[(size_t)row * N_DIM + col] = (float)iacc[fi][fj][r] * rs + bvs;
      }
    }
  }
}

// ---------------- fallback: fused bf16 dequant GEMM (no workspace needed) ----------------
__global__ __launch_bounds__(256, 2) void gemm_fused_kernel(
    const float* __restrict__ x, const int* __restrict__ q,
    const float* __restrict__ s, const float* __restrict__ bias,
    float* __restrict__ C) {
  __shared__ unsigned short As[BM * BK];
  __shared__ unsigned short Bs[BN * BK];

  const int tid = threadIdx.x;
  const int wave = tid >> 6, lane = tid & 63;
  const int m0 = blockIdx.y * BM, n0 = blockIdx.x * BN;
  const int wm = (wave >> 1) * 64, wn = (wave & 1) * 64;

  f32x4 acc[4][4] = {};

  const int r2 = tid >> 1;
  const int kh = (tid & 1) * 32;
  const float* xg = x + (size_t)(m0 + r2) * K_DIM + kh;
  const int* qg = q + (size_t)(n0 + r2) * KB2 + (tid & 1) * 16;
  const float* sg = s + (size_t)(n0 + r2) * NGRP;
  unsigned short* Asp = &As[r2 * BK + kh];
  unsigned short* Bsp = &Bs[r2 * BK + kh];

  const int lane16 = lane & 15;
  const int kq = (lane >> 4) * 8;

  for (int t = 0; t < K_DIM / BK; ++t) {
    union { unsigned short h[8]; bf16x8 v; } oA[4], oB[4];
#pragma unroll
    for (int j = 0; j < 4; ++j) {
      float4 f0 = *(const float4*)(xg + t * BK + j * 8);
      float4 f1 = *(const float4*)(xg + t * BK + j * 8 + 4);
      oA[j].h[0] = f2bf(f0.x); oA[j].h[1] = f2bf(f0.y); oA[j].h[2] = f2bf(f0.z); oA[j].h[3] = f2bf(f0.w);
      oA[j].h[4] = f2bf(f1.x); oA[j].h[5] = f2bf(f1.y); oA[j].h[6] = f2bf(f1.z); oA[j].h[7] = f2bf(f1.w);
    }
    float sc = sg[t >> 1];
#pragma unroll
    for (int j = 0; j < 4; ++j) {
      int4 qv = *(const int4*)(qg + t * 32 + j * 4);
      int b;
      b = qv.x; oB[j].h[0] = f2bf((float)((b & 15) - 8) * sc); oB[j].h[1] = f2bf((float)(((b >> 4) & 15) - 8) * sc);
      b = qv.y; oB[j].h[2] = f2bf((float)((b & 15) - 8) * sc); oB[j].h[3] = f2bf((float)(((b >> 4) & 15) - 8) * sc);
      b = qv.z; oB[j].h[4] = f2bf((float)((b & 15) - 8) * sc); oB[j].h[5] = f2bf((float)(((b >> 4) & 15) - 8) * sc);
      b = qv.w; oB[j].h[6] = f2bf((float)((b & 15) - 8) * sc); oB[j].h[7] = f2bf((float)(((b >> 4) & 15) - 8) * sc);
    }
    __syncthreads();
#pragma unroll
    for (int j = 0; j < 4; ++j) {
      *(bf16x8*)(Asp + j * 8) = oA[j].v;
      *(bf16x8*)(Bsp + j * 8) = oB[j].v;
    }
    __syncthreads();
#pragma unroll
    for (int kk = 0; kk < 2; ++kk) {
      const int ko = kk * 32 + kq;
      bf16x8 av[4], bv[4];
#pragma unroll
      for (int i = 0; i < 4; ++i)
        av[i] = *(const bf16x8*)&As[(wm + i * 16 + lane16) * BK + ko];
#pragma unroll
      for (int i = 0; i < 4; ++i)
        bv[i] = *(const bf16x8*)&Bs[(wn + i * 16 + lane16) * BK + ko];
#pragma unroll
      for (int i = 0; i < 4; ++i)
#pragma unroll
        for (int j = 0; j < 4; ++j)
          acc[i][j] = __builtin_amdgcn_mfma_f32_16x16x32_bf16(av[i], bv[j], acc[i][j], 0, 0, 0);
    }
  }

  const int col0 = n0 + wn + lane16;
  const int row0 = m0 + wm + (lane >> 4) * 4;
#pragma unroll
  for (int j = 0; j < 4; ++j) {
    float bvs = bias[col0 + j * 16];
#pragma unroll
    for (int i = 0; i < 4; ++i) {
#pragma unroll
      for (int r = 0; r < 4; ++r) {
        C[(size_t)(row0 + i * 16 + r) * N_DIM + (col0 + j * 16)] = acc[i][j][r] + bvs;
      }
    }
  }
}

extern "C" void kernel_launch(void* const* d_in, const int* in_sizes, int n_in,
                              void* d_out, int out_size, void* d_ws, size_t ws_size,
                              hipStream_t stream) {
  const float* x = (const float*)d_in[0];
  const int* q = (const int*)d_in[1];
  const float* s = (const float*)d_in[2];
  const float* b = (const float*)d_in[3];
  float* out = (float*)d_out;

  const size_t w_bytes = (size_t)N_DIM * K_DIM;          // 45,088,768 (i8 W)
  const size_t x_bytes = (size_t)M_DIM * K_DIM;          // 8,388,608  (i8 x)
  const size_t r_bytes = (size_t)N_DIM * 4;              // 44,032 each
  const size_t need = w_bytes + x_bytes + 2 * r_bytes;   // ~54 MB

  if (ws_size >= need) {
    signed char* Wq = (signed char*)d_ws;
    signed char* Xq = Wq + w_bytes;
    float* d_inv = (float*)(Wq + w_bytes + x_bytes);
    float* rowScale = d_inv + N_DIM;
    quant_x_kernel<<<dim3(2048), dim3(256), 0, stream>>>(x, Xq);
    rowscale_kernel<<<dim3((N_DIM + 255) / 256), dim3(256), 0, stream>>>(s, d_inv, rowScale);
    unpack_w_kernel<<<dim3(2048), dim3(256), 0, stream>>>(q, s, d_inv, Wq);
    gemm_i8_kernel<<<dim3((N_DIM / TBN) * (M_DIM / TBM)), dim3(512), 0, stream>>>(Xq, Wq, rowScale, b, out);
  } else {
    gemm_fused_kernel<<<dim3(N_DIM / BN, M_DIM / BM), dim3(256), 0, stream>>>(x, q, s, b, out);
  }
}

// Round 16
// 155.259 us; speedup vs baseline: 1.2289x; 1.0330x over previous
//
#include <hip/hip_runtime.h>
#include <stdint.h>

// QuantizedLinear: out = x @ dequant(q,s)^T + bias
// Pure-i8 path. R16 = R15 (R11 skeleton + mfma_i32_32x32x32_i8) with the
// LDS swizzle FIXED for the 32x32 read pattern:
//   R15 bug: required k-chunk c = 2ks+(lane>>5) is constant in lane bits 3,4,
//   so p = c^(row&7) put lanes {l,l+8,l+16,l+24} in the SAME slot -> 4-way
//   bank conflict (measured 1.127e7, +4.0cy/read; m136 predicts +4.6 ✓).
//   Fix: p = c ^ (row&7) ^ ((row>>3)&3)  (absorbs row bits 3,4; bijective).
// Applied both-sides: staging global-k inverse + ds_read slot.
#define M_DIM 2048
#define K_DIM 4096
#define N_DIM 11008
#define KB2   (K_DIM / 2)
#define NGRP  32

#define TBM 128
#define TBN 256
#define TBK 128
#define NT  (K_DIM / TBK)     // 32 K-steps
#define BUF_B 49152           // bytes per LDS buffer: A 128x128 (16KB) + B 256x128 (32KB)

#define XRANGE 5.0f
#define XSCALE (127.0f / XRANGE)
#define XINV   (XRANGE / 127.0f)

// fallback tile (bf16 fused path, no workspace)
#define BM 128
#define BN 128
#define BK 64

typedef __attribute__((ext_vector_type(4)))  int   i32x4;
typedef __attribute__((ext_vector_type(16))) int   i32x16;
typedef __attribute__((ext_vector_type(4)))  float f32x4;
typedef __attribute__((ext_vector_type(8)))  short bf16x8;

__device__ __forceinline__ unsigned short f2bf(float f) {
  union { float f; unsigned u; } v; v.f = f;
  return (unsigned short)((v.u + 0x7FFFu + ((v.u >> 16) & 1u)) >> 16);
}

__device__ __forceinline__ void gload_lds16(const void* g, void* l) {
  __builtin_amdgcn_global_load_lds(
      (__attribute__((address_space(1))) void*)(g),
      (__attribute__((address_space(3))) void*)(l), 16, 0, 0);
}

__device__ __forceinline__ int q127(float v) {
  float qf = fminf(127.0f, fmaxf(-127.0f, rintf(v * XSCALE)));
  return (int)qf;
}

// ---------------- prepass: x f32 -> i8 (fixed scale) ----------------
__global__ void quant_x_kernel(const float* __restrict__ x,
                               signed char* __restrict__ xq) {
  const size_t total = (size_t)M_DIM * K_DIM / 16;
  for (size_t u = (size_t)blockIdx.x * blockDim.x + threadIdx.x; u < total;
       u += (size_t)gridDim.x * blockDim.x) {
    const float4* src = (const float4*)(x + u * 16);
    int4 o;
    int* op = (int*)&o;
#pragma unroll
    for (int i = 0; i < 4; ++i) {
      float4 f = src[i];
      int q0 = q127(f.x), q1 = q127(f.y), q2 = q127(f.z), q3 = q127(f.w);
      op[i] = (q0 & 255) | ((q1 & 255) << 8) | ((q2 & 255) << 16) | ((q3 & 255) << 24);
    }
    *(int4*)(xq + u * 16) = o;
  }
}

// ---------------- prepass: per-row scale prep ----------------
__global__ void rowscale_kernel(const float* __restrict__ s,
                                float* __restrict__ d_inv,
                                float* __restrict__ rowScale) {
  int o = blockIdx.x * blockDim.x + threadIdx.x;
  if (o >= N_DIM) return;
  const float4* sp = (const float4*)(s + o * NGRP);
  float m = 0.0f;
#pragma unroll
  for (int i = 0; i < 8; ++i) {
    float4 v = sp[i];
    m = fmaxf(m, fmaxf(fmaxf(v.x, v.y), fmaxf(v.z, v.w)));
  }
  float d = 8.0f * m / 127.0f;
  d_inv[o] = 1.0f / d;
  rowScale[o] = d * XINV;
}

// ---------------- prepass: packed int4 -> requantized i8 W [N, K] ----------------
__global__ void unpack_w_kernel(const int* __restrict__ q,
                                const float* __restrict__ s,
                                const float* __restrict__ d_inv,
                                signed char* __restrict__ W) {
  const size_t total = (size_t)N_DIM * KB2 / 8;
  for (size_t u = (size_t)blockIdx.x * blockDim.x + threadIdx.x; u < total;
       u += (size_t)gridDim.x * blockDim.x) {
    size_t qi = u * 8;
    unsigned o = (unsigned)(qi >> 11);
    unsigned c = (unsigned)(qi & 2047);
    float sc = s[o * NGRP + (c >> 6)] * d_inv[o];
    int4 v0 = *(const int4*)(q + qi);
    int4 v1 = *(const int4*)(q + qi + 4);
    int4 out;
    int* op = (int*)&out;
#pragma unroll
    for (int i = 0; i < 2; ++i) {
      const int* vv = i ? (const int*)&v1 : (const int*)&v0;
#pragma unroll
      for (int p = 0; p < 2; ++p) {
        int a = vv[p * 2], b = vv[p * 2 + 1];
        int q0 = (int)rintf((float)((a & 15) - 8) * sc);
        int q1 = (int)rintf((float)(((a >> 4) & 15) - 8) * sc);
        int q2 = (int)rintf((float)((b & 15) - 8) * sc);
        int q3 = (int)rintf((float)(((b >> 4) & 15) - 8) * sc);
        op[i * 2 + p] = (q0 & 255) | ((q1 & 255) << 8) | ((q2 & 255) << 16) | ((q3 & 255) << 24);
      }
    }
    *(int4*)(W + qi * 2) = out;
  }
}

// ---------------- main GEMM: C = Xq * Wq^T (i8), epilogue row scale + bias ----------------
// 128x256 tile, BK=128, 8 waves (2M x 4N), wave 64x64 = 2x2 frags of 32x32.
// mfma_i32_32x32x32_i8; per step 16 ds_read_b128 + 16 MFMA.
// 3-buffer LDS rotation, distance-2 prefetch, counted vmcnt(6) at step end.
// Swizzle (R16 fix): LDS[row][p] holds k-chunk p ^ (row&7) ^ ((row>>3)&3).
__global__ __launch_bounds__(512, 2) void gemm_i8_kernel(
    const signed char* __restrict__ A, const signed char* __restrict__ B,
    const float* __restrict__ rowScale, const float* __restrict__ bias,
    float* __restrict__ C) {
  __shared__ signed char lds[3 * BUF_B];  // 144 KB

  const int tid = threadIdx.x;
  const int w = tid >> 6, lane = tid & 63;

  // T1: XCD-chunked bijective swizzle (688 = 8 * 86), m-fast within XCD.
  const int hw = blockIdx.x;
  const int wg = (hw & 7) * 86 + (hw >> 3);
  const int m0 = (wg % 16) * TBM;
  const int n0 = (wg / 16) * TBN;

  // staging: 6 issues/tile (A:2, B:4), 512 thr x 16B = 64 rows each.
  // row srow = tid>>3 (issue bases are multiples of 64 -> contribute 0 to
  // both swizzle fields). phys slot = tid&7; global k-chunk =
  // slot ^ (srow&7) ^ ((srow>>3)&3) = (tid&7) ^ ((tid>>3)&7) ^ ((tid>>6)&3).
  const int srow = tid >> 3;
  const int kx = (((tid & 7) ^ ((tid >> 3) & 7) ^ ((tid >> 6) & 3)) << 4);  // bytes
  const signed char* Ag = A + (size_t)(m0 + srow) * K_DIM + kx;
  const signed char* Bg = B + (size_t)(n0 + srow) * K_DIM + kx;
  const int wBase = w * 1024;  // wave-uniform LDS staging base (bytes)

#define STAGE(bufo, t2) {                                                      \
    const signed char* a_ = Ag + (size_t)(t2) * TBK;                           \
    const signed char* b_ = Bg + (size_t)(t2) * TBK;                           \
    gload_lds16(a_,                       lds + (bufo) + wBase);               \
    gload_lds16(a_ + (size_t)64 * K_DIM,  lds + (bufo) + 8192 + wBase);        \
    gload_lds16(b_,                       lds + (bufo) + 16384 + wBase);       \
    gload_lds16(b_ + (size_t)64 * K_DIM,  lds + (bufo) + 24576 + wBase);       \
    gload_lds16(b_ + (size_t)128 * K_DIM, lds + (bufo) + 32768 + wBase);       \
    gload_lds16(b_ + (size_t)192 * K_DIM, lds + (bufo) + 40960 + wBase);       \
  }

  // ds_read addressing: 32x32 frag f, k-slice ks; needed k-chunk
  // c = 2ks + (lane>>5); row = base + (lane&31), row&7 = lane&7,
  // (row>>3)&3 = (lane31>>3)&3 (bases are multiples of 64).
  // phys slot p = c ^ (lane&7) ^ ((lane31>>3)&3)  -> byte = row*128 + p*16.
  const int lane31 = lane & 31, lhi = lane >> 5, l7 = lane & 7;
  const int l43 = (lane31 >> 3) & 3;
  const int wm = (w >> 2) * 64, wn = (w & 3) * 64;
  int aOff[2][4], bOff[2][4];
#pragma unroll
  for (int f = 0; f < 2; ++f)
#pragma unroll
    for (int ks = 0; ks < 4; ++ks) {
      const int sl = ((((ks << 1) | lhi) ^ l7 ^ l43) << 4);
      aOff[f][ks] = (wm + f * 32 + lane31) * 128 + sl;
      bOff[f][ks] = 16384 + (wn + f * 32 + lane31) * 128 + sl;
    }

  i32x16 iacc[2][2];
#pragma unroll
  for (int i = 0; i < 2; ++i)
#pragma unroll
    for (int j = 0; j < 2; ++j)
#pragma unroll
      for (int r = 0; r < 16; ++r) iacc[i][j][r] = 0;

  // prologue: tiles 0,1 (12 loads); wait until only tile1's 6 remain
  STAGE(0, 0);
  STAGE(BUF_B, 1);
  asm volatile("s_waitcnt vmcnt(6)" ::: "memory");
  __builtin_amdgcn_s_barrier();

  int cur = 0, stg = 2 * BUF_B;
  for (int t = 0; t < NT; ++t) {
    if (t + 2 < NT) STAGE(stg, t + 2);

    const signed char* Lb = lds + cur;
    i32x4 av[2][4], bv[2][4];
#pragma unroll
    for (int f = 0; f < 2; ++f)
#pragma unroll
      for (int ks = 0; ks < 4; ++ks) {
        av[f][ks] = *(const i32x4*)(Lb + aOff[f][ks]);
        bv[f][ks] = *(const i32x4*)(Lb + bOff[f][ks]);
      }

    __builtin_amdgcn_s_setprio(1);
#pragma unroll
    for (int ks = 0; ks < 4; ++ks)
#pragma unroll
      for (int fi = 0; fi < 2; ++fi)
#pragma unroll
        for (int fj = 0; fj < 2; ++fj)
          iacc[fi][fj] = __builtin_amdgcn_mfma_i32_32x32x32_i8(
              av[fi][ks], bv[fj][ks], iacc[fi][fj], 0, 0, 0);
    __builtin_amdgcn_s_setprio(0);

    if (t == NT - 1) break;
    if (t == NT - 2) {
      asm volatile("s_waitcnt vmcnt(0)" ::: "memory");  // final tile must land
    } else {
      asm volatile("s_waitcnt vmcnt(6)" ::: "memory");  // keep tile t+2 in flight
    }
    __builtin_amdgcn_s_barrier();
    cur = (cur == 2 * BUF_B) ? 0 : cur + BUF_B;
    stg = (stg == 2 * BUF_B) ? 0 : stg + BUF_B;
  }
#undef STAGE

  // epilogue: 32x32 D mapping (m74/m101-verified): col = lane&31,
  // row = (reg&3) + 8*(reg>>2) + 4*(lane>>5), reg in [0,16).
  const int rowb = m0 + wm + 4 * lhi;
  const int col0 = n0 + wn + lane31;
#pragma unroll
  for (int fj = 0; fj < 2; ++fj) {
    const int col = col0 + fj * 32;
    float rs = rowScale[col];
    float bvs = bias[col];
#pragma unroll
    for (int fi = 0; fi < 2; ++fi) {
#pragma unroll
      for (int r = 0; r < 16; ++r) {
        const int row = rowb + fi * 32 + (r & 3) + 8 * (r >> 2);
        C[(size_t)row * N_DIM + col] = (float)iacc[fi][fj][r] * rs + bvs;
      }
    }
  }
}

// ---------------- fallback: fused bf16 dequant GEMM (no workspace needed) ----------------
__global__ __launch_bounds__(256, 2) void gemm_fused_kernel(
    const float* __restrict__ x, const int* __restrict__ q,
    const float* __restrict__ s, const float* __restrict__ bias,
    float* __restrict__ C) {
  __shared__ unsigned short As[BM * BK];
  __shared__ unsigned short Bs[BN * BK];

  const int tid = threadIdx.x;
  const int wave = tid >> 6, lane = tid & 63;
  const int m0 = blockIdx.y * BM, n0 = blockIdx.x * BN;
  const int wm = (wave >> 1) * 64, wn = (wave & 1) * 64;

  f32x4 acc[4][4] = {};

  const int r2 = tid >> 1;
  const int kh = (tid & 1) * 32;
  const float* xg = x + (size_t)(m0 + r2) * K_DIM + kh;
  const int* qg = q + (size_t)(n0 + r2) * KB2 + (tid & 1) * 16;
  const float* sg = s + (size_t)(n0 + r2) * NGRP;
  unsigned short* Asp = &As[r2 * BK + kh];
  unsigned short* Bsp = &Bs[r2 * BK + kh];

  const int lane16 = lane & 15;
  const int kq = (lane >> 4) * 8;

  for (int t = 0; t < K_DIM / BK; ++t) {
    union { unsigned short h[8]; bf16x8 v; } oA[4], oB[4];
#pragma unroll
    for (int j = 0; j < 4; ++j) {
      float4 f0 = *(const float4*)(xg + t * BK + j * 8);
      float4 f1 = *(const float4*)(xg + t * BK + j * 8 + 4);
      oA[j].h[0] = f2bf(f0.x); oA[j].h[1] = f2bf(f0.y); oA[j].h[2] = f2bf(f0.z); oA[j].h[3] = f2bf(f0.w);
      oA[j].h[4] = f2bf(f1.x); oA[j].h[5] = f2bf(f1.y); oA[j].h[6] = f2bf(f1.z); oA[j].h[7] = f2bf(f1.w);
    }
    float sc = sg[t >> 1];
#pragma unroll
    for (int j = 0; j < 4; ++j) {
      int4 qv = *(const int4*)(qg + t * 32 + j * 4);
      int b;
      b = qv.x; oB[j].h[0] = f2bf((float)((b & 15) - 8) * sc); oB[j].h[1] = f2bf((float)(((b >> 4) & 15) - 8) * sc);
      b = qv.y; oB[j].h[2] = f2bf((float)((b & 15) - 8) * sc); oB[j].h[3] = f2bf((float)(((b >> 4) & 15) - 8) * sc);
      b = qv.z; oB[j].h[4] = f2bf((float)((b & 15) - 8) * sc); oB[j].h[5] = f2bf((float)(((b >> 4) & 15) - 8) * sc);
      b = qv.w; oB[j].h[6] = f2bf((float)((b & 15) - 8) * sc); oB[j].h[7] = f2bf((float)(((b >> 4) & 15) - 8) * sc);
    }
    __syncthreads();
#pragma unroll
    for (int j = 0; j < 4; ++j) {
      *(bf16x8*)(Asp + j * 8) = oA[j].v;
      *(bf16x8*)(Bsp + j * 8) = oB[j].v;
    }
    __syncthreads();
#pragma unroll
    for (int kk = 0; kk < 2; ++kk) {
      const int ko = kk * 32 + kq;
      bf16x8 av[4], bv[4];
#pragma unroll
      for (int i = 0; i < 4; ++i)
        av[i] = *(const bf16x8*)&As[(wm + i * 16 + lane16) * BK + ko];
#pragma unroll
      for (int i = 0; i < 4; ++i)
        bv[i] = *(const bf16x8*)&Bs[(wn + i * 16 + lane16) * BK + ko];
#pragma unroll
      for (int i = 0; i < 4; ++i)
#pragma unroll
        for (int j = 0; j < 4; ++j)
          acc[i][j] = __builtin_amdgcn_mfma_f32_16x16x32_bf16(av[i], bv[j], acc[i][j], 0, 0, 0);
    }
  }

  const int col0 = n0 + wn + lane16;
  const int row0 = m0 + wm + (lane >> 4) * 4;
#pragma unroll
  for (int j = 0; j < 4; ++j) {
    float bvs = bias[col0 + j * 16];
#pragma unroll
    for (int i = 0; i < 4; ++i) {
#pragma unroll
      for (int r = 0; r < 4; ++r) {
        C[(size_t)(row0 + i * 16 + r) * N_DIM + (col0 + j * 16)] = acc[i][j][r] + bvs;
      }
    }
  }
}

extern "C" void kernel_launch(void* const* d_in, const int* in_sizes, int n_in,
                              void* d_out, int out_size, void* d_ws, size_t ws_size,
                              hipStream_t stream) {
  const float* x = (const float*)d_in[0];
  const int* q = (const int*)d_in[1];
  const float* s = (const float*)d_in[2];
  const float* b = (const float*)d_in[3];
  float* out = (float*)d_out;

  const size_t w_bytes = (size_t)N_DIM * K_DIM;          // 45,088,768 (i8 W)
  const size_t x_bytes = (size_t)M_DIM * K_DIM;          // 8,388,608  (i8 x)
  const size_t r_bytes = (size_t)N_DIM * 4;              // 44,032 each
  const size_t need = w_bytes + x_bytes + 2 * r_bytes;   // ~54 MB

  if (ws_size >= need) {
    signed char* Wq = (signed char*)d_ws;
    signed char* Xq = Wq + w_bytes;
    float* d_inv = (float*)(Wq + w_bytes + x_bytes);
    float* rowScale = d_inv + N_DIM;
    quant_x_kernel<<<dim3(2048), dim3(256), 0, stream>>>(x, Xq);
    rowscale_kernel<<<dim3((N_DIM + 255) / 256), dim3(256), 0, stream>>>(s, d_inv, rowScale);
    unpack_w_kernel<<<dim3(2048), dim3(256), 0, stream>>>(q, s, d_inv, Wq);
    gemm_i8_kernel<<<dim3((N_DIM / TBN) * (M_DIM / TBM)), dim3(512), 0, stream>>>(Xq, Wq, rowScale, b, out);
  } else {
    gemm_fused_kernel<<<dim3(N_DIM / BN, M_DIM / BM), dim3(256), 0, stream>>>(x, q, s, b, out);
  }
}

// Round 17
// 147.173 us; speedup vs baseline: 1.2964x; 1.0549x over previous
//
#include <hip/hip_runtime.h>
#include <stdint.h>

// QuantizedLinear: out = x @ dequant(q,s)^T + bias
// FINAL (R11 restored — session best, 145.5µs total / 122.5µs GEMM):
// Pure-i8 path: group scales folded INTO the i8 weight requantization
// (w_i8 = rint((nib-8)*s[o][g]*127/(8*smax_o)), per-row scale d_o), x
// quantized at fixed scale -> GEMM is a single i32-accumulator i8 MFMA
// chain over all K. Epilogue: out = iacc * rowScale[col] + bias[col].
// Skeleton: 128x256 tile, BK=128, 8 waves (2Mx4N, wave 64x64),
// mfma_i32_16x16x64_i8, 3-buffer LDS rotation, distance-2 prefetch,
// counted s_waitcnt vmcnt(6) (never 0 in steady state), both-sides
// XOR swizzle (slot ^= row&7) -> 0 bank conflicts, T1 XCD-chunked grid.
#define M_DIM 2048
#define K_DIM 4096
#define N_DIM 11008
#define KB2   (K_DIM / 2)
#define NGRP  32

#define TBM 128
#define TBN 256
#define TBK 128
#define NT  (K_DIM / TBK)     // 32 K-steps
#define BUF_B 49152           // bytes per LDS buffer: A 128x128 (16KB) + B 256x128 (32KB)

#define XRANGE 5.0f
#define XSCALE (127.0f / XRANGE)
#define XINV   (XRANGE / 127.0f)

// fallback tile (bf16 fused path, no workspace)
#define BM 128
#define BN 128
#define BK 64

typedef __attribute__((ext_vector_type(4))) int   i32x4;
typedef __attribute__((ext_vector_type(4))) float f32x4;
typedef __attribute__((ext_vector_type(8))) short bf16x8;

__device__ __forceinline__ unsigned short f2bf(float f) {
  union { float f; unsigned u; } v; v.f = f;
  return (unsigned short)((v.u + 0x7FFFu + ((v.u >> 16) & 1u)) >> 16);
}

__device__ __forceinline__ void gload_lds16(const void* g, void* l) {
  __builtin_amdgcn_global_load_lds(
      (__attribute__((address_space(1))) void*)(g),
      (__attribute__((address_space(3))) void*)(l), 16, 0, 0);
}

__device__ __forceinline__ int q127(float v) {
  float qf = fminf(127.0f, fmaxf(-127.0f, rintf(v * XSCALE)));
  return (int)qf;
}

// ---------------- prepass: x f32 -> i8 (fixed scale) ----------------
__global__ void quant_x_kernel(const float* __restrict__ x,
                               signed char* __restrict__ xq) {
  const size_t total = (size_t)M_DIM * K_DIM / 16;
  for (size_t u = (size_t)blockIdx.x * blockDim.x + threadIdx.x; u < total;
       u += (size_t)gridDim.x * blockDim.x) {
    const float4* src = (const float4*)(x + u * 16);
    int4 o;
    int* op = (int*)&o;
#pragma unroll
    for (int i = 0; i < 4; ++i) {
      float4 f = src[i];
      int q0 = q127(f.x), q1 = q127(f.y), q2 = q127(f.z), q3 = q127(f.w);
      op[i] = (q0 & 255) | ((q1 & 255) << 8) | ((q2 & 255) << 16) | ((q3 & 255) << 24);
    }
    *(int4*)(xq + u * 16) = o;
  }
}

// ---------------- prepass: per-row scale prep ----------------
// d_inv[o] = 127/(8*smax_o)  (for W requant); rowScale[o] = (8*smax_o/127)*XINV
__global__ void rowscale_kernel(const float* __restrict__ s,
                                float* __restrict__ d_inv,
                                float* __restrict__ rowScale) {
  int o = blockIdx.x * blockDim.x + threadIdx.x;
  if (o >= N_DIM) return;
  const float4* sp = (const float4*)(s + o * NGRP);
  float m = 0.0f;
#pragma unroll
  for (int i = 0; i < 8; ++i) {
    float4 v = sp[i];
    m = fmaxf(m, fmaxf(fmaxf(v.x, v.y), fmaxf(v.z, v.w)));
  }
  float d = 8.0f * m / 127.0f;
  d_inv[o] = 1.0f / d;
  rowScale[o] = d * XINV;
}

// ---------------- prepass: packed int4 -> requantized i8 W [N, K] ----------------
// w_i8 = rint((nib-8) * s[o][g] * d_inv[o]); |w_i8| <= 127 by construction.
__global__ void unpack_w_kernel(const int* __restrict__ q,
                                const float* __restrict__ s,
                                const float* __restrict__ d_inv,
                                signed char* __restrict__ W) {
  const size_t total = (size_t)N_DIM * KB2 / 8;
  for (size_t u = (size_t)blockIdx.x * blockDim.x + threadIdx.x; u < total;
       u += (size_t)gridDim.x * blockDim.x) {
    size_t qi = u * 8;
    unsigned o = (unsigned)(qi >> 11);
    unsigned c = (unsigned)(qi & 2047);
    float sc = s[o * NGRP + (c >> 6)] * d_inv[o];
    int4 v0 = *(const int4*)(q + qi);
    int4 v1 = *(const int4*)(q + qi + 4);
    int4 out;
    int* op = (int*)&out;
#pragma unroll
    for (int i = 0; i < 2; ++i) {
      const int* vv = i ? (const int*)&v1 : (const int*)&v0;
#pragma unroll
      for (int p = 0; p < 2; ++p) {
        int a = vv[p * 2], b = vv[p * 2 + 1];
        int q0 = (int)rintf((float)((a & 15) - 8) * sc);
        int q1 = (int)rintf((float)(((a >> 4) & 15) - 8) * sc);
        int q2 = (int)rintf((float)((b & 15) - 8) * sc);
        int q3 = (int)rintf((float)(((b >> 4) & 15) - 8) * sc);
        op[i * 2 + p] = (q0 & 255) | ((q1 & 255) << 8) | ((q2 & 255) << 16) | ((q3 & 255) << 24);
      }
    }
    *(int4*)(W + qi * 2) = out;
  }
}

// ---------------- main GEMM: C = Xq * Wq^T (i8), epilogue row scale + bias ----------------
// 128x256 tile, BK=128, 8 waves (2M x 4N), wave 64x64 = iacc[4][4] (i32),
// single accumulator chain across all 32 K-steps (|sum| << 2^31).
// Per step per wave: 16 ds_read_b128 + 6 gload_lds + 32 MFMA (compiler-interleaved).
// 3-buffer LDS rotation, distance-2 prefetch, counted vmcnt(6) at step end.
// Swizzle for 128B rows (8 x 16B slots), both-sides: slot ^= row&7 -> conflict-free.
__global__ __launch_bounds__(512, 2) void gemm_i8_kernel(
    const signed char* __restrict__ A, const signed char* __restrict__ B,
    const float* __restrict__ rowScale, const float* __restrict__ bias,
    float* __restrict__ C) {
  __shared__ signed char lds[3 * BUF_B];  // 144 KB

  const int tid = threadIdx.x;
  const int w = tid >> 6, lane = tid & 63;

  // T1: XCD-chunked bijective swizzle (688 = 8 * 86), m-fast within XCD.
  const int hw = blockIdx.x;
  const int wg = (hw & 7) * 86 + (hw >> 3);
  const int m0 = (wg % 16) * TBM;
  const int n0 = (wg / 16) * TBN;

  // staging: 6 issues/tile (A:2, B:4), each issue = 512 thr x 16B = 8KB = 64 rows.
  // thread row-within-issue = tid>>3, 16B slot = tid&7.
  // Inverse swizzle on global k: slot s of row r holds k-chunk s ^ (r&7).
  const int srow = tid >> 3;
  const int kx = (((tid & 7) ^ ((tid >> 3) & 7)) << 4);  // bytes
  const signed char* Ag = A + (size_t)(m0 + srow) * K_DIM + kx;
  const signed char* Bg = B + (size_t)(n0 + srow) * K_DIM + kx;
  const int wBase = w * 1024;  // wave-uniform LDS staging base (bytes)

#define STAGE(bufo, t2) {                                                      \
    const signed char* a_ = Ag + (size_t)(t2) * TBK;                           \
    const signed char* b_ = Bg + (size_t)(t2) * TBK;                           \
    gload_lds16(a_,                       lds + (bufo) + wBase);               \
    gload_lds16(a_ + (size_t)64 * K_DIM,  lds + (bufo) + 8192 + wBase);        \
    gload_lds16(b_,                       lds + (bufo) + 16384 + wBase);       \
    gload_lds16(b_ + (size_t)64 * K_DIM,  lds + (bufo) + 24576 + wBase);       \
    gload_lds16(b_ + (size_t)128 * K_DIM, lds + (bufo) + 32768 + wBase);       \
    gload_lds16(b_ + (size_t)192 * K_DIM, lds + (bufo) + 40960 + wBase);       \
  }

  // ds_read addressing (swizzled): byte = row*128 + ((kk*4+lq) ^ (row&7))*16
  const int lane16 = lane & 15, lq = lane >> 4;
  const int wm = (w >> 2) * 64, wn = (w & 3) * 64;
  int aOff[4][2], bOff[4][2];
#pragma unroll
  for (int i = 0; i < 4; ++i)
#pragma unroll
    for (int kk = 0; kk < 2; ++kk) {
      const int sl = ((kk * 4 + lq) ^ (lane16 & 7)) << 4;
      aOff[i][kk] = (wm + i * 16 + lane16) * 128 + sl;
      bOff[i][kk] = 16384 + (wn + i * 16 + lane16) * 128 + sl;
    }

  i32x4 iacc[4][4];
#pragma unroll
  for (int i = 0; i < 4; ++i)
#pragma unroll
    for (int j = 0; j < 4; ++j) iacc[i][j] = (i32x4){0, 0, 0, 0};

  // prologue: tiles 0,1 (12 loads); wait until only tile1's 6 remain
  STAGE(0, 0);
  STAGE(BUF_B, 1);
  asm volatile("s_waitcnt vmcnt(6)" ::: "memory");
  __builtin_amdgcn_s_barrier();

  int cur = 0, stg = 2 * BUF_B;
  for (int t = 0; t < NT; ++t) {
    if (t + 2 < NT) STAGE(stg, t + 2);

    const signed char* Lb = lds + cur;
    i32x4 av[4][2], bv[4][2];
#pragma unroll
    for (int i = 0; i < 4; ++i)
#pragma unroll
      for (int kk = 0; kk < 2; ++kk) {
        av[i][kk] = *(const i32x4*)(Lb + aOff[i][kk]);
        bv[i][kk] = *(const i32x4*)(Lb + bOff[i][kk]);
      }

    __builtin_amdgcn_s_setprio(1);
#pragma unroll
    for (int u = 0; u < 16; ++u) {
      const int pi = u & 3, pj = u >> 2;
      i32x4 tmp_ = __builtin_amdgcn_mfma_i32_16x16x64_i8(av[pi][0], bv[pj][0],
                                                         iacc[pi][pj], 0, 0, 0);
      iacc[pi][pj] = __builtin_amdgcn_mfma_i32_16x16x64_i8(av[pi][1], bv[pj][1],
                                                           tmp_, 0, 0, 0);
    }
    __builtin_amdgcn_s_setprio(0);

    if (t == NT - 1) break;
    if (t == NT - 2) {
      asm volatile("s_waitcnt vmcnt(0)" ::: "memory");  // final tile must land
    } else {
      asm volatile("s_waitcnt vmcnt(6)" ::: "memory");  // keep tile t+2 in flight
    }
    __builtin_amdgcn_s_barrier();
    cur = (cur == 2 * BUF_B) ? 0 : cur + BUF_B;
    stg = (stg == 2 * BUF_B) ? 0 : stg + BUF_B;
  }
#undef STAGE

  // epilogue: D mapping col=lane&15, row=(lane>>4)*4+r
  const int row0 = m0 + wm + (lane >> 4) * 4;
  const int col0 = n0 + wn + lane16;
#pragma unroll
  for (int j = 0; j < 4; ++j) {
    const int col = col0 + j * 16;
    float rs = rowScale[col];
    float bvs = bias[col];
#pragma unroll
    for (int i = 0; i < 4; ++i) {
#pragma unroll
      for (int r = 0; r < 4; ++r) {
        C[(size_t)(row0 + i * 16 + r) * N_DIM + col] =
            (float)iacc[i][j][r] * rs + bvs;
      }
    }
  }
}

// ---------------- fallback: fused bf16 dequant GEMM (no workspace needed) ----------------
__global__ __launch_bounds__(256, 2) void gemm_fused_kernel(
    const float* __restrict__ x, const int* __restrict__ q,
    const float* __restrict__ s, const float* __restrict__ bias,
    float* __restrict__ C) {
  __shared__ unsigned short As[BM * BK];
  __shared__ unsigned short Bs[BN * BK];

  const int tid = threadIdx.x;
  const int wave = tid >> 6, lane = tid & 63;
  const int m0 = blockIdx.y * BM, n0 = blockIdx.x * BN;
  const int wm = (wave >> 1) * 64, wn = (wave & 1) * 64;

  f32x4 acc[4][4] = {};

  const int r2 = tid >> 1;
  const int kh = (tid & 1) * 32;
  const float* xg = x + (size_t)(m0 + r2) * K_DIM + kh;
  const int* qg = q + (size_t)(n0 + r2) * KB2 + (tid & 1) * 16;
  const float* sg = s + (size_t)(n0 + r2) * NGRP;
  unsigned short* Asp = &As[r2 * BK + kh];
  unsigned short* Bsp = &Bs[r2 * BK + kh];

  const int lane16 = lane & 15;
  const int kq = (lane >> 4) * 8;

  for (int t = 0; t < K_DIM / BK; ++t) {
    union { unsigned short h[8]; bf16x8 v; } oA[4], oB[4];
#pragma unroll
    for (int j = 0; j < 4; ++j) {
      float4 f0 = *(const float4*)(xg + t * BK + j * 8);
      float4 f1 = *(const float4*)(xg + t * BK + j * 8 + 4);
      oA[j].h[0] = f2bf(f0.x); oA[j].h[1] = f2bf(f0.y); oA[j].h[2] = f2bf(f0.z); oA[j].h[3] = f2bf(f0.w);
      oA[j].h[4] = f2bf(f1.x); oA[j].h[5] = f2bf(f1.y); oA[j].h[6] = f2bf(f1.z); oA[j].h[7] = f2bf(f1.w);
    }
    float sc = sg[t >> 1];
#pragma unroll
    for (int j = 0; j < 4; ++j) {
      int4 qv = *(const int4*)(qg + t * 32 + j * 4);
      int b;
      b = qv.x; oB[j].h[0] = f2bf((float)((b & 15) - 8) * sc); oB[j].h[1] = f2bf((float)(((b >> 4) & 15) - 8) * sc);
      b = qv.y; oB[j].h[2] = f2bf((float)((b & 15) - 8) * sc); oB[j].h[3] = f2bf((float)(((b >> 4) & 15) - 8) * sc);
      b = qv.z; oB[j].h[4] = f2bf((float)((b & 15) - 8) * sc); oB[j].h[5] = f2bf((float)(((b >> 4) & 15) - 8) * sc);
      b = qv.w; oB[j].h[6] = f2bf((float)((b & 15) - 8) * sc); oB[j].h[7] = f2bf((float)(((b >> 4) & 15) - 8) * sc);
    }
    __syncthreads();
#pragma unroll
    for (int j = 0; j < 4; ++j) {
      *(bf16x8*)(Asp + j * 8) = oA[j].v;
      *(bf16x8*)(Bsp + j * 8) = oB[j].v;
    }
    __syncthreads();
#pragma unroll
    for (int kk = 0; kk < 2; ++kk) {
      const int ko = kk * 32 + kq;
      bf16x8 av[4], bv[4];
#pragma unroll
      for (int i = 0; i < 4; ++i)
        av[i] = *(const bf16x8*)&As[(wm + i * 16 + lane16) * BK + ko];
#pragma unroll
      for (int i = 0; i < 4; ++i)
        bv[i] = *(const bf16x8*)&Bs[(wn + i * 16 + lane16) * BK + ko];
#pragma unroll
      for (int i = 0; i < 4; ++i)
#pragma unroll
        for (int j = 0; j < 4; ++j)
          acc[i][j] = __builtin_amdgcn_mfma_f32_16x16x32_bf16(av[i], bv[j], acc[i][j], 0, 0, 0);
    }
  }

  const int col0 = n0 + wn + lane16;
  const int row0 = m0 + wm + (lane >> 4) * 4;
#pragma unroll
  for (int j = 0; j < 4; ++j) {
    float bvs = bias[col0 + j * 16];
#pragma unroll
    for (int i = 0; i < 4; ++i) {
#pragma unroll
      for (int r = 0; r < 4; ++r) {
        C[(size_t)(row0 + i * 16 + r) * N_DIM + (col0 + j * 16)] = acc[i][j][r] + bvs;
      }
    }
  }
}

extern "C" void kernel_launch(void* const* d_in, const int* in_sizes, int n_in,
                              void* d_out, int out_size, void* d_ws, size_t ws_size,
                              hipStream_t stream) {
  const float* x = (const float*)d_in[0];
  const int* q = (const int*)d_in[1];
  const float* s = (const float*)d_in[2];
  const float* b = (const float*)d_in[3];
  float* out = (float*)d_out;

  const size_t w_bytes = (size_t)N_DIM * K_DIM;          // 45,088,768 (i8 W)
  const size_t x_bytes = (size_t)M_DIM * K_DIM;          // 8,388,608  (i8 x)
  const size_t r_bytes = (size_t)N_DIM * 4;              // 44,032 each
  const size_t need = w_bytes + x_bytes + 2 * r_bytes;   // ~54 MB

  if (ws_size >= need) {
    signed char* Wq = (signed char*)d_ws;
    signed char* Xq = Wq + w_bytes;
    float* d_inv = (float*)(Wq + w_bytes + x_bytes);
    float* rowScale = d_inv + N_DIM;
    quant_x_kernel<<<dim3(2048), dim3(256), 0, stream>>>(x, Xq);
    rowscale_kernel<<<dim3((N_DIM + 255) / 256), dim3(256), 0, stream>>>(s, d_inv, rowScale);
    unpack_w_kernel<<<dim3(2048), dim3(256), 0, stream>>>(q, s, d_inv, Wq);
    gemm_i8_kernel<<<dim3((N_DIM / TBN) * (M_DIM / TBM)), dim3(512), 0, stream>>>(Xq, Wq, rowScale, b, out);
  } else {
    gemm_fused_kernel<<<dim3(N_DIM / BN, M_DIM / BM), dim3(256), 0, stream>>>(x, q, s, b, out);
  }
}